// Round 15
// baseline (320.308 us; speedup 1.0000x reference)
//
#include <hip/hip_runtime.h>
#include <math.h>

// ClassificationBackbone: conv/attn pipeline.
// R15: conv grid reorder — ocg INNERMOST so the 8 (or 4) oc-groups of the
// same input tile run as consecutive blocks and share the patch through
// L1/L2 (kills the 4x input over-fetch seen in R14: FETCH 49.6MB for a
// 12.5MB input). Everything else unchanged from R14.

#define DEVINL __device__ __forceinline__

using bf16x8 = __attribute__((ext_vector_type(8))) short;  // 8 bf16 (4 VGPRs)
using f32x4 = __attribute__((ext_vector_type(4))) float;   // 4 fp32

DEVINL float selu_f(float x) {
  const float scale = 1.0507009873554805f;
  const float alpha = 1.6732632423543772f;
  return scale * (x > 0.f ? x : alpha * (__expf(x) - 1.f));
}

DEVINL short f2bf(float f) {  // RNE fp32 -> bf16
  unsigned int u = __float_as_uint(f);
  u = (u + 0x7FFFu + ((u >> 16) & 1u)) >> 16;
  return (short)u;
}

// ---------------- prep: h = concat([x^0.25/255^0.25, x], batch) -------------
__global__ __launch_bounds__(256) void k_prep(const float* __restrict__ x,
                                              float* __restrict__ h, int n) {
  const float invScale = 0.250244727f;  // 255^-0.25
  for (int i = blockIdx.x * blockDim.x + threadIdx.x; i < n;
       i += gridDim.x * blockDim.x) {
    float v = x[i];
    h[i] = sqrtf(sqrtf(v)) * invScale;
    h[n + i] = v;
  }
}

// ---------- direct conv3x3 (no LDS): 2x2 quad x OCB ocs per thread ----------
// blockIdx = (b, quad-tile, ocg) with ocg INNERMOST: consecutive blocks
// process the same input tile for different oc-groups -> L1/L2 sharing.
// Weights wave-uniform -> s_load. POOL: quad -> 1 pooled output/oc.
// Patch loads always in-bounds (2*qmax+3 <= IW-1 for all shapes used);
// all float2 addresses 8B-aligned (even strides/bases).
template <bool POOL, bool DO_SELU, bool DO_BIAS, int OCB>
__global__ __launch_bounds__(256) void k_conv3x3d(
    const float* __restrict__ in, const float* __restrict__ w,
    const float* __restrict__ bias, float* __restrict__ outA,
    float* __restrict__ outB, int splitB, int Bn, int Cin, int Cout, int IH,
    int IW, int nQB) {
  const int CH = IH - 2, CW = IW - 2;
  const int OH = POOL ? (CH >> 1) : CH;
  const int OW = POOL ? (CW >> 1) : CW;
  const int QY = POOL ? OH : (CH >> 1);
  const int QX = POOL ? OW : (CW >> 1);
  const int nQ = QY * QX;
  const int nOcg = Cout / OCB;

  int bid = blockIdx.x;
  const int ocg = bid % nOcg; bid /= nOcg;   // innermost: share input tile
  const int qblk = bid % nQB;
  const int b = bid / nQB;
  const int oc0 = ocg * OCB;

  const int q = qblk * 256 + threadIdx.x;
  if (q >= nQ) return;
  const int qx = q % QX;
  const int qy = q / QX;
  const int iy = 2 * qy, ix = 2 * qx;

  const float* ib = in + ((long)b * Cin * IH + iy) * IW + ix;

  float acc[OCB][2][2];
#pragma unroll
  for (int o = 0; o < OCB; ++o)
#pragma unroll
    for (int r = 0; r < 2; ++r)
#pragma unroll
      for (int c = 0; c < 2; ++c) acc[o][r][c] = 0.f;

  for (int ci = 0; ci < Cin; ++ci) {
    float pr[4][4];
    const float* p = ib + (long)ci * IH * IW;
#pragma unroll
    for (int r = 0; r < 4; ++r) {
      const float2 u0 = *(const float2*)(p + (long)r * IW);
      const float2 u1 = *(const float2*)(p + (long)r * IW + 2);
      pr[r][0] = u0.x; pr[r][1] = u0.y; pr[r][2] = u1.x; pr[r][3] = u1.y;
    }
    const float* wc = w + ((long)oc0 * Cin + ci) * 9;  // wave-uniform
#pragma unroll
    for (int o = 0; o < OCB; ++o) {
      const float* wp = wc + (long)o * Cin * 9;
#pragma unroll
      for (int ky = 0; ky < 3; ++ky)
#pragma unroll
        for (int kx = 0; kx < 3; ++kx) {
          const float ww = wp[ky * 3 + kx];
#pragma unroll
          for (int r = 0; r < 2; ++r)
#pragma unroll
            for (int c = 0; c < 2; ++c)
              acc[o][r][c] = fmaf(ww, pr[r + ky][c + kx], acc[o][r][c]);
        }
    }
  }

  if (POOL) {
#pragma unroll
    for (int o = 0; o < OCB; ++o) {
      const float bb = DO_BIAS ? bias[oc0 + o] : 0.f;
      float s = 0.f;
#pragma unroll
      for (int r = 0; r < 2; ++r)
#pragma unroll
        for (int c = 0; c < 2; ++c) {
          float v = acc[o][r][c] + bb;
          if (DO_SELU) v = selu_f(v);
          s += v;
        }
      const float rv = 0.25f * s;
      const int oc = oc0 + o;
      if (outB != nullptr && b >= splitB)
        outB[(((long)(b - splitB) * Cout + oc) * OH + qy) * OW + qx] = rv;
      else
        outA[(((long)b * Cout + oc) * OH + qy) * OW + qx] = rv;
    }
  } else {
#pragma unroll
    for (int o = 0; o < OCB; ++o) {
      const float bb = DO_BIAS ? bias[oc0 + o] : 0.f;
      const int oc = oc0 + o;
#pragma unroll
      for (int r = 0; r < 2; ++r)
#pragma unroll
        for (int c = 0; c < 2; ++c) {
          const int oy = iy + r, ox = ix + c;
          float v = acc[o][r][c] + bb;
          if (DO_SELU) v = selu_f(v);
          float* dst =
              (outB != nullptr && b >= splitB)
                  ? &outB[(((long)(b - splitB) * Cout + oc) * OH + oy) * OW + ox]
                  : &outA[(((long)b * Cout + oc) * OH + oy) * OW + ox];
          *dst = v;
        }
    }
  }
}

// -------- qkv for MFMA attention -------------------------------------------
// qtb,ktb bf16 [Np][8]. V written PRE-PERMUTED into PV-fragment order:
// vp[((b*ntile + t)*CB + cb)*512 + lane*8 + i], lane = g*16 + (c&15),
// t = n>>5, mo = n&31, g = (mo&15)>>2, i = ((mo>>4)<<2) | (mo&3), cb = c>>4.
template <int CB>
__global__ __launch_bounds__(256) void k_qkvA(
    const float* __restrict__ x, const float* __restrict__ wq,
    const float* __restrict__ bq, const float* __restrict__ wk,
    const float* __restrict__ bk, const float* __restrict__ wv,
    const float* __restrict__ bv, unsigned short* __restrict__ qtb,
    unsigned short* __restrict__ ktb, unsigned short* __restrict__ vp,
    int Bn, int C, int D, int N, int Np) {
  constexpr int Cpad = CB * 16;
  const int ntile = Np >> 5;
  const int seg1 = Np * 8;
  const int S = 2 * seg1 + Cpad * Np;
  const int total = Bn * S;
  for (int idx = blockIdx.x * blockDim.x + threadIdx.x; idx < total;
       idx += gridDim.x * blockDim.x) {
    const int b = idx / S;
    const int rr = idx % S;
    const float* xb = x + (long)b * C * N;
    if (rr < 2 * seg1) {
      const bool isq = rr < seg1;
      const int t = isq ? rr : rr - seg1;
      const int n = t >> 3, co = t & 7;
      unsigned short val = 0;
      if (co < D && n < N) {
        const float* w = (isq ? wq : wk) + co * C;
        float a = (isq ? bq : bk)[co];
        for (int ci = 0; ci < C; ++ci) a = fmaf(w[ci], xb[(long)ci * N + n], a);
        val = (unsigned short)f2bf(a);
      }
      (isq ? qtb : ktb)[((long)b * Np + n) * 8 + co] = val;
    } else {
      const int t2 = rr - 2 * seg1;
      const int c = t2 / Np, n = t2 % Np;
      unsigned short v = 0;
      if (c < C && n < N) {
        const float* w = wv + c * C;
        float a = bv[c];
        for (int ci = 0; ci < C; ++ci) a = fmaf(w[ci], xb[(long)ci * N + n], a);
        v = (unsigned short)f2bf(a);
      }
      const int tt = n >> 5, mo = n & 31;
      const int g = (mo & 15) >> 2;
      const int i = ((mo >> 4) << 2) | (mo & 3);
      const int lane = g * 16 + (c & 15);
      const int cb = c >> 4;
      vp[(((long)b * ntile + tt) * CB + cb) * 512 + lane * 8 + i] = v;
    }
  }
}

// ---------------- full-MFMA flash attention + residual ----------------
template <int C, int CB>
__global__ __launch_bounds__(256) void k_attnN(
    const float* __restrict__ x, const unsigned short* __restrict__ qtb,
    const unsigned short* __restrict__ ktb,
    const unsigned short* __restrict__ vp,
    const float* __restrict__ gamma_p, float* __restrict__ out, int N, int Np,
    int nqt) {
  __shared__ float pO[4][CB * 256];
  __shared__ float pD[4][16];

  const int bid = blockIdx.x;
  const int b = bid / nqt;
  const int n0 = (bid % nqt) * 16;
  const int tid = threadIdx.x;
  const int wv_ = tid >> 6;
  const int lane = tid & 63;
  const int g = lane >> 4;
  const int qi = lane & 15;

  const int ntile = Np >> 5;
  const unsigned short* qb_ = qtb + (long)b * Np * 8;
  const unsigned short* kb_ = ktb + (long)b * Np * 8;
  const unsigned short* vb_ = vp + (long)b * ntile * CB * 512 + lane * 8;

  bf16x8 qf;
#pragma unroll
  for (int i = 0; i < 8; ++i) qf[i] = 0;
  if (g == 0) qf = *(const bf16x8*)(qb_ + (long)(n0 + qi) * 8);

  f32x4 acc[CB];
#pragma unroll
  for (int cb = 0; cb < CB; ++cb) {
    f32x4 z = {0.f, 0.f, 0.f, 0.f};
    acc[cb] = z;
  }
  float den = 0.f;
  const f32x4 z4 = {0.f, 0.f, 0.f, 0.f};

  for (int t = wv_; t < ntile; t += 4) {
    const int mb = t * 32;
    bf16x8 kf0, kf1;
#pragma unroll
    for (int i = 0; i < 8; ++i) { kf0[i] = 0; kf1[i] = 0; }
    if (g == 0) {
      kf0 = *(const bf16x8*)(kb_ + (long)(mb + qi) * 8);
      kf1 = *(const bf16x8*)(kb_ + (long)(mb + 16 + qi) * 8);
    }
    const f32x4 e0 =
        __builtin_amdgcn_mfma_f32_16x16x32_bf16(kf0, qf, z4, 0, 0, 0);
    const f32x4 e1 =
        __builtin_amdgcn_mfma_f32_16x16x32_bf16(kf1, qf, z4, 0, 0, 0);

    bf16x8 pb;
#pragma unroll
    for (int r = 0; r < 4; ++r) {
      const int ma = mb + 4 * g + r;
      const int mc = ma + 16;
      const float p0 = (ma < N) ? __expf(e0[r]) : 0.f;
      const float p1 = (mc < N) ? __expf(e1[r]) : 0.f;
      den += p0 + p1;
      pb[r] = f2bf(p0);
      pb[4 + r] = f2bf(p1);
    }
    const unsigned short* vt_ = vb_ + (long)t * CB * 512;
#pragma unroll
    for (int cb = 0; cb < CB; ++cb) {
      const bf16x8 va = *(const bf16x8*)(vt_ + cb * 512);
      acc[cb] =
          __builtin_amdgcn_mfma_f32_16x16x32_bf16(va, pb, acc[cb], 0, 0, 0);
    }
  }

  den += __shfl_xor(den, 16, 64);
  den += __shfl_xor(den, 32, 64);

#pragma unroll
  for (int cb = 0; cb < CB; ++cb)
#pragma unroll
    for (int r = 0; r < 4; ++r)
      pO[wv_][cb * 256 + (4 * g + r) * 16 + qi] = acc[cb][r];
  if (g == 0) pD[wv_][qi] = den;
  __syncthreads();

  const float gma = gamma_p[0];
#pragma unroll
  for (int cb = 0; cb < CB; ++cb) {
    const int cell = cb * 256 + tid;
    const int c = cb * 16 + (tid >> 4);
    const int q = tid & 15;
    const int n = n0 + q;
    if (c < C && n < N) {
      const float s = pO[0][cell] + pO[1][cell] + pO[2][cell] + pO[3][cell];
      const float Dn = pD[0][q] + pD[1][q] + pD[2][q] + pD[3][q];
      const long o = ((long)b * C + c) * N + n;
      out[o] = fmaf(gma, s / Dn, x[o]);
    }
  }
}

// ---------------- q/k/v projections (attn3 small path) ----------------
template <int Cp>
__global__ __launch_bounds__(256) void k_qkv3(
    const float* __restrict__ x, const float* __restrict__ wq,
    const float* __restrict__ bq, const float* __restrict__ wk,
    const float* __restrict__ bk, const float* __restrict__ wv,
    const float* __restrict__ bv, float* __restrict__ qt,
    float* __restrict__ kt, float* __restrict__ vt, int Bn, int C, int D,
    int N, int Np) {
  constexpr int KP = 8;
  const int S = Np * (2 * KP + Cp);
  const int total = Bn * S;
  for (int idx = blockIdx.x * blockDim.x + threadIdx.x; idx < total;
       idx += gridDim.x * blockDim.x) {
    const int b = idx / S;
    const int rr = idx % S;
    const float* xb = x + (long)b * C * N;
    const float* w = nullptr;
    const float* bp = nullptr;
    float* dst;
    int n, co, lim;
    if (rr < Np * KP) {
      n = rr / KP; co = rr % KP; lim = D;
      w = wq + co * C; bp = bq;
      dst = qt + ((long)b * Np + n) * KP + co;
    } else if (rr < 2 * Np * KP) {
      const int t = rr - Np * KP;
      n = t / KP; co = t % KP; lim = D;
      w = wk + co * C; bp = bk;
      dst = kt + ((long)b * Np + n) * KP + co;
    } else {
      const int t = rr - 2 * Np * KP;
      n = t / Cp; co = t % Cp; lim = C;
      w = wv + co * C; bp = bv;
      dst = vt + ((long)b * Np + n) * Cp + co;
    }
    if (co < lim && n < N) {
      float a = bp[co];
      for (int ci = 0; ci < C; ++ci) a = fmaf(w[ci], xb[(long)ci * N + n], a);
      *dst = a;
    } else {
      *dst = 0.f;
    }
  }
}

// ---------------- flash attention partials (attn3 small path) ---------------
template <int C, int Chp>
__global__ __launch_bounds__(128) void k_attn7(
    const float* __restrict__ qt, const float* __restrict__ kt,
    const float* __restrict__ vt, float* __restrict__ num,
    float* __restrict__ den, int N, int nbr, int S, int msz, int Np, int Nr) {
  constexpr int KP = 8;
  constexpr int Cp = 2 * Chp;
  constexpr int NV = Chp / 4;
  int bid = blockIdx.x;
  const int s = bid % S; bid /= S;
  const int rb = bid % nbr;
  const int b = bid / nbr;
  const int brow = rb * 32;
  const int tid = threadIdx.x;
  const int lane = tid & 63;
  const int cg = tid >> 6;
  const int g = lane >> 4;
  const int r = lane & 15;

  const float* qb = qt + (long)b * Np * KP;
  const float* kb = kt + (long)b * Np * KP;
  const float* vb = vt + (long)b * Np * Cp;

  float4 q0[2];
  float2 q1[2];
#pragma unroll
  for (int k = 0; k < 2; ++k) {
    const int n = brow + r + 16 * k;
    q0[k] = *(const float4*)(qb + (long)n * KP);
    q1[k] = *(const float2*)(qb + (long)n * KP + 4);
  }

  float acc[2][Chp];
#pragma unroll
  for (int k = 0; k < 2; ++k)
#pragma unroll
    for (int c = 0; c < Chp; ++c) acc[k][c] = 0.f;
  float sm[2] = {0.f, 0.f};

  const int mstart = s * msz;
  const int mlimit = min(mstart + msz, N);
  for (int m0 = mstart; m0 < mlimit; m0 += 4) {
    const int m = m0 + g;
    const float4 ka = *(const float4*)(kb + (long)m * KP);
    const float2 kc = *(const float2*)(kb + (long)m * KP + 4);
    float4 vv[NV];
    const float4* vpp = (const float4*)(vb + (long)m * Cp + cg * Chp);
#pragma unroll
    for (int j = 0; j < NV; ++j) vv[j] = vpp[j];
#pragma unroll
    for (int k = 0; k < 2; ++k) {
      float e = q0[k].x * ka.x;
      e = fmaf(q0[k].y, ka.y, e);
      e = fmaf(q0[k].z, ka.z, e);
      e = fmaf(q0[k].w, ka.w, e);
      e = fmaf(q1[k].x, kc.x, e);
      e = fmaf(q1[k].y, kc.y, e);
      const float p = __expf(e);
      sm[k] += p;
#pragma unroll
      for (int j = 0; j < NV; ++j) {
        acc[k][4 * j + 0] = fmaf(p, vv[j].x, acc[k][4 * j + 0]);
        acc[k][4 * j + 1] = fmaf(p, vv[j].y, acc[k][4 * j + 1]);
        acc[k][4 * j + 2] = fmaf(p, vv[j].z, acc[k][4 * j + 2]);
        acc[k][4 * j + 3] = fmaf(p, vv[j].w, acc[k][4 * j + 3]);
      }
    }
  }

#pragma unroll
  for (int k = 0; k < 2; ++k) {
    sm[k] += __shfl_xor(sm[k], 16, 64);
    sm[k] += __shfl_xor(sm[k], 32, 64);
#pragma unroll
    for (int c = 0; c < Chp; ++c) {
      acc[k][c] += __shfl_xor(acc[k][c], 16, 64);
      acc[k][c] += __shfl_xor(acc[k][c], 32, 64);
    }
  }

  if (g == 0) {
    float* np_ = num + ((long)(s * 8 + b) * Cp + cg * Chp) * Nr;
    float* dp_ = den + (long)(s * 8 + b) * Nr;
#pragma unroll
    for (int k = 0; k < 2; ++k) {
      const int n = brow + r + 16 * k;
      if (n < N) {
#pragma unroll
        for (int c = 0; c < Chp; ++c) np_[(long)c * Nr + n] = acc[k][c];
        if (cg == 0) dp_[n] = sm[k];
      }
    }
  }
}

// ---------------- attention merge (attn3 small path) ----------------
__global__ __launch_bounds__(256) void k_attnmerge(
    const float* __restrict__ x, const float* __restrict__ num,
    const float* __restrict__ den, const float* __restrict__ gamma_p,
    float* __restrict__ out, int C, int Cp, int N, int Nr, int S) {
  const float g = gamma_p[0];
  const int total = 8 * C * N;
  for (int idx = blockIdx.x * blockDim.x + threadIdx.x; idx < total;
       idx += gridDim.x * blockDim.x) {
    const int n = idx % N;
    const int t = idx / N;
    const int c = t % C;
    const int b = t / C;
    float a = 0.f, d = 0.f;
    for (int s = 0; s < S; ++s) {
      a += num[((long)(s * 8 + b) * Cp + c) * Nr + n];
      d += den[(long)(s * 8 + b) * Nr + n];
    }
    out[((long)b * C + c) * N + n] =
        fmaf(g, a / d, x[((long)b * C + c) * N + n]);
  }
}

// ---------------- batchnorm stats: mean + rsqrt(var+eps) per channel --------
__global__ __launch_bounds__(256) void k_bnstats(const float* __restrict__ x,
                                                 float* __restrict__ stats,
                                                 int Bn, int C, int HW,
                                                 float eps) {
  int c = blockIdx.x;
  int tid = threadIdx.x;
  int cnt = Bn * HW;
  float s = 0.f, s2 = 0.f;
  for (int i = tid; i < cnt; i += blockDim.x) {
    int b = i / HW, r = i % HW;
    float v = x[((long)b * C + c) * HW + r];
    s += v;
    s2 += v * v;
  }
#pragma unroll
  for (int off = 32; off > 0; off >>= 1) {
    s += __shfl_down(s, off);
    s2 += __shfl_down(s2, off);
  }
  __shared__ float as_[4], as2_[4];
  int wid = tid >> 6;
  if ((tid & 63) == 0) { as_[wid] = s; as2_[wid] = s2; }
  __syncthreads();
  if (tid == 0) {
    float S = 0.f, S2 = 0.f;
#pragma unroll
    for (int ww = 0; ww < 4; ++ww) { S += as_[ww]; S2 += as2_[ww]; }
    float mean = S / (float)cnt;
    float var = S2 / (float)cnt - mean * mean;
    stats[c] = mean;
    stats[C + c] = rsqrtf(var + eps);
  }
}

// ---------------- BN apply + selu (+pool) ----------------
template <bool POOL>
__global__ __launch_bounds__(256) void k_bn_selu(
    const float* __restrict__ x, const float* __restrict__ stats,
    const float* __restrict__ g, const float* __restrict__ beta,
    float* __restrict__ out, int Bn, int C, int IH, int IW) {
  int OH = POOL ? (IH >> 1) : IH;
  int OW = POOL ? (IW >> 1) : IW;
  int total = Bn * C * OH * OW;
  for (int idx = blockIdx.x * blockDim.x + threadIdx.x; idx < total;
       idx += gridDim.x * blockDim.x) {
    int px = idx % OW;
    int t = idx / OW;
    int py = t % OH;
    t /= OH;
    int c = t % C;
    int b = t / C;
    float mean = stats[c], istd = stats[C + c];
    float gg = g[c], bb = beta[c];
    const float* ip = x + ((long)b * C + c) * IH * IW;
    float r;
    if (POOL) {
      int iy = py * 2, ix = px * 2;
      float v00 = selu_f((ip[iy * IW + ix] - mean) * istd * gg + bb);
      float v01 = selu_f((ip[iy * IW + ix + 1] - mean) * istd * gg + bb);
      float v10 = selu_f((ip[(iy + 1) * IW + ix] - mean) * istd * gg + bb);
      float v11 = selu_f((ip[(iy + 1) * IW + ix + 1] - mean) * istd * gg + bb);
      r = 0.25f * (v00 + v01 + v10 + v11);
    } else {
      r = selu_f((ip[py * IW + px] - mean) * istd * gg + bb);
    }
    out[((b * C + c) * OH + py) * OW + px] = r;
  }
}

static inline int gs(int total) { return (total + 255) / 256; }
static inline int cdiv(int a, int b) { return (a + b - 1) / b; }

extern "C" void kernel_launch(void* const* d_in, const int* in_sizes, int n_in,
                              void* d_out, int out_size, void* d_ws,
                              size_t ws_size, hipStream_t stream) {
  const float* x      = (const float*)d_in[0];
  const float* enc_w1 = (const float*)d_in[1];
  const float* enc_b1 = (const float*)d_in[2];
  const float* enc_w2 = (const float*)d_in[3];
  const float* enc_b2 = (const float*)d_in[4];
  const float* a1_wq  = (const float*)d_in[5];
  const float* a1_bq  = (const float*)d_in[6];
  const float* a1_wk  = (const float*)d_in[7];
  const float* a1_bk  = (const float*)d_in[8];
  const float* a1_wv  = (const float*)d_in[9];
  const float* a1_bv  = (const float*)d_in[10];
  const float* a1_g   = (const float*)d_in[11];
  const float* c1_w   = (const float*)d_in[12];
  const float* c1_b   = (const float*)d_in[13];
  const float* a2_wq  = (const float*)d_in[14];
  const float* a2_bq  = (const float*)d_in[15];
  const float* a2_wk  = (const float*)d_in[16];
  const float* a2_bk  = (const float*)d_in[17];
  const float* a2_wv  = (const float*)d_in[18];
  const float* a2_bv  = (const float*)d_in[19];
  const float* a2_g   = (const float*)d_in[20];
  const float* c2_w   = (const float*)d_in[21];
  const float* c2_b   = (const float*)d_in[22];
  const float* c3_w   = (const float*)d_in[23];
  const float* c3_g   = (const float*)d_in[24];
  const float* c3_be  = (const float*)d_in[25];
  const float* c4_w   = (const float*)d_in[26];
  const float* c4_g   = (const float*)d_in[27];
  const float* c4_be  = (const float*)d_in[28];
  const float* a3_wq  = (const float*)d_in[29];
  const float* a3_bq  = (const float*)d_in[30];
  const float* a3_wk  = (const float*)d_in[31];
  const float* a3_bk  = (const float*)d_in[32];
  const float* a3_wv  = (const float*)d_in[33];
  const float* a3_bv  = (const float*)d_in[34];
  const float* a3_g   = (const float*)d_in[35];

  float* out = (float*)d_out;
  float* W = (float*)d_ws;

  // ---- workspace plan (float slots; peak 5,056,320 = 20.2 MB, proven) ----
  float* h    = W;                         // [0, 1,920,000)
  float* h1   = W + 1920000;               // [1,920,000, 5,056,320)
  float* h2   = W;                         // [0, 737,280)
  float* xenc = out + 5120;                // (8,40,48,48) direct

  // attn1: Np1=2304, CB=3
  unsigned short* qtb1 = (unsigned short*)(W + 737280);   // 147,456 bf16
  unsigned short* ktb1 = (unsigned short*)(W + 884736);   // 147,456 bf16
  unsigned short* vtb1 = (unsigned short*)(W + 1032192);  // 884,736 bf16
  float* at1 = W + 1474560;                // 737,280 -> ends 2,211,840
  float* c1o = W + 2211840;                // 846,400 -> ends 3,058,240

  // attn2: Np2=2144, CB=4
  unsigned short* qtb2 = (unsigned short*)(W + 3058240);  // 137,216 bf16
  unsigned short* ktb2 = (unsigned short*)(W + 3195456);  // 137,216 bf16
  unsigned short* vtb2 = (unsigned short*)(W + 3332672);  // 1,097,728 bf16
  float* at2 = W + 3881536;                // 846,400 -> ends 4,727,936

  float* c2o  = W;                         // 154,880
  float* c3o  = W + 200000;                // 96,000
  float* st3  = W + 300000;                // 60
  float* c3p  = W + 310000;                // 24,000
  float* c4o  = W + 340000;                // 5,120
  float* st4  = W + 350000;                // 20
  float* c4b  = W + 360000;                // 5,120
  float* q3   = W + 370000;                // 8,192
  float* k3   = W + 380000;                // 8,192
  float* v3   = W + 390000;                // 16,384
  float* num3 = W + 410000;                // 8,192
  float* den3 = W + 420000;                // 512

  const int NOSPLIT = 1 << 30;

  // 1. prep
  {
    int n = 8 * 3 * 200 * 200;
    k_prep<<<gs(n), 256, 0, stream>>>(x, h, n);
  }
  // 2. enc conv1 + selu + pool : (16,3,200,200)->(16,20,99,99), direct OCB=5
  {
    int nQ = 99 * 99;
    int nQB = cdiv(nQ, 256);               // 39
    int blocks = 16 * (20 / 5) * nQB;      // 2496
    k_conv3x3d<true, true, true, 5><<<blocks, 256, 0, stream>>>(
        h, enc_w1, enc_b1, h1, nullptr, NOSPLIT, 16, 3, 20, 200, 200, nQB);
  }
  // 3. enc conv2 + selu + pool : (16,20,99,99)->(16,40,48,48), direct OCB=5
  {
    int nQ = 48 * 48;
    int nQB = cdiv(nQ, 256);               // 9
    int blocks = 16 * (40 / 5) * nQB;      // 1152
    k_conv3x3d<true, true, true, 5><<<blocks, 256, 0, stream>>>(
        h1, enc_w2, enc_b2, h2, xenc, 8, 16, 20, 40, 99, 99, nQB);
  }
  // 4. attn1 qkv : CB=3, Np=2304
  {
    int total = 8 * 2304 * (16 + 48);
    k_qkvA<3><<<gs(total), 256, 0, stream>>>(h2, a1_wq, a1_bq, a1_wk, a1_bk,
                                             a1_wv, a1_bv, qtb1, ktb1, vtb1,
                                             8, 40, 5, 2304, 2304);
  }
  // 5. attn1 (full MFMA, coalesced V) : C=40, CB=3, nqt=144
  {
    k_attnN<40, 3><<<8 * 144, 256, 0, stream>>>(h2, qtb1, ktb1, vtb1, a1_g,
                                                at1, 2304, 2304, 144);
  }
  // 6. c1 conv + selu : (8,40,48,48)->(8,50,46,46), direct OCB=2
  {
    int nQ = 23 * 23;                      // quads over 46x46
    int nQB = cdiv(nQ, 256);               // 3
    int blocks = 8 * (50 / 2) * nQB;       // 600
    k_conv3x3d<false, true, true, 2><<<blocks, 256, 0, stream>>>(
        at1, c1_w, c1_b, c1o, nullptr, NOSPLIT, 8, 40, 50, 48, 48, nQB);
  }
  // 7. attn2 qkv : CB=4, Np=2144
  {
    int total = 8 * 2144 * (16 + 64);
    k_qkvA<4><<<gs(total), 256, 0, stream>>>(c1o, a2_wq, a2_bq, a2_wk, a2_bk,
                                             a2_wv, a2_bv, qtb2, ktb2, vtb2,
                                             8, 50, 6, 2116, 2144);
  }
  // 8. attn2 (full MFMA, coalesced V) : C=50, CB=4, nqt=133
  {
    k_attnN<50, 4><<<8 * 133, 256, 0, stream>>>(c1o, qtb2, ktb2, vtb2, a2_g,
                                                at2, 2116, 2144, 133);
  }
  // 9. c2 conv + selu + pool : (8,50,46,46)->(8,40,22,22), direct OCB=2
  {
    int nQ = 22 * 22;                      // pooled outputs
    int nQB = cdiv(nQ, 256);               // 2
    int blocks = 8 * (40 / 2) * nQB;       // 320
    k_conv3x3d<true, true, true, 2><<<blocks, 256, 0, stream>>>(
        at2, c2_w, c2_b, c2o, nullptr, NOSPLIT, 8, 50, 40, 46, 46, nQB);
  }
  // 10. c3 conv : (8,40,22,22)->(8,30,20,20), direct OCB=2
  {
    int nQ = 10 * 10;
    int nQB = cdiv(nQ, 256);               // 1
    int blocks = 8 * (30 / 2) * nQB;       // 120
    k_conv3x3d<false, false, false, 2><<<blocks, 256, 0, stream>>>(
        c2o, c3_w, nullptr, c3o, nullptr, NOSPLIT, 8, 40, 30, 22, 22, nQB);
  }
  // 11-12. BN(c3) + selu + pool -> (8,30,10,10)
  k_bnstats<<<30, 256, 0, stream>>>(c3o, st3, 8, 30, 400, 1e-5f);
  {
    int total = 8 * 30 * 10 * 10;
    k_bn_selu<true><<<gs(total), 256, 0, stream>>>(c3o, st3, c3_g, c3_be, c3p,
                                                   8, 30, 20, 20);
  }
  // 13. c4 conv : (8,30,10,10)->(8,10,8,8), direct OCB=2
  {
    int nQ = 4 * 4;
    int nQB = cdiv(nQ, 256);               // 1
    int blocks = 8 * (10 / 2) * nQB;       // 40
    k_conv3x3d<false, false, false, 2><<<blocks, 256, 0, stream>>>(
        c3p, c4_w, nullptr, c4o, nullptr, NOSPLIT, 8, 30, 10, 10, 10, nQB);
  }
  // 14-15. BN(c4) + selu
  k_bnstats<<<10, 256, 0, stream>>>(c4o, st4, 8, 10, 64, 1e-5f);
  {
    int total = 8 * 10 * 8 * 8;
    k_bn_selu<false><<<gs(total), 256, 0, stream>>>(c4o, st4, c4_g, c4_be, c4b,
                                                    8, 10, 8, 8);
  }
  // 16. attn3 qkv : Cp=16, Np=128
  {
    int total = 8 * 128 * (16 + 16);
    k_qkv3<16><<<gs(total), 256, 0, stream>>>(c4b, a3_wq, a3_bq, a3_wk, a3_bk,
                                              a3_wv, a3_bv, q3, k3, v3, 8, 10,
                                              1, 64, 128);
  }
  // 17. attn3 partials + merge -> out[0..5120)
  {
    int nbr = 2, S = 1, msz = 64;
    k_attn7<10, 8><<<8 * nbr * S, 128, 0, stream>>>(q3, k3, v3, num3, den3, 64,
                                                    nbr, S, msz, 128, 64);
    k_attnmerge<<<gs(8 * 10 * 64), 256, 0, stream>>>(c4b, num3, den3, a3_g,
                                                     out, 10, 16, 64, 64, S);
  }
}

// Round 16
// 313.924 us; speedup vs baseline: 1.0203x; 1.0203x over previous
//
#include <hip/hip_runtime.h>
#include <math.h>

// ClassificationBackbone: conv/attn pipeline.
// R16: conv grid XCD-stride fix. Dispatch round-robins blocks over 8 XCDs
// (bid%8), so R15's ocg-adjacent ordering put tile replicas on DIFFERENT
// L2s (no sharing; FETCH unchanged). Now bid = ocg*(Bn*nQB) + b*nQB + qblk:
// ocg stride (Bn*nQB) is divisible by 8 for every layer, so all oc-group
// replicas of a tile land on the SAME XCD and share its L2.

#define DEVINL __device__ __forceinline__

using bf16x8 = __attribute__((ext_vector_type(8))) short;  // 8 bf16 (4 VGPRs)
using f32x4 = __attribute__((ext_vector_type(4))) float;   // 4 fp32

DEVINL float selu_f(float x) {
  const float scale = 1.0507009873554805f;
  const float alpha = 1.6732632423543772f;
  return scale * (x > 0.f ? x : alpha * (__expf(x) - 1.f));
}

DEVINL short f2bf(float f) {  // RNE fp32 -> bf16
  unsigned int u = __float_as_uint(f);
  u = (u + 0x7FFFu + ((u >> 16) & 1u)) >> 16;
  return (short)u;
}

// ---------------- prep: h = concat([x^0.25/255^0.25, x], batch) -------------
__global__ __launch_bounds__(256) void k_prep(const float* __restrict__ x,
                                              float* __restrict__ h, int n) {
  const float invScale = 0.250244727f;  // 255^-0.25
  for (int i = blockIdx.x * blockDim.x + threadIdx.x; i < n;
       i += gridDim.x * blockDim.x) {
    float v = x[i];
    h[i] = sqrtf(sqrtf(v)) * invScale;
    h[n + i] = v;
  }
}

// ---------- direct conv3x3 (no LDS): 2x2 quad x OCB ocs per thread ----------
// bid = ocg*(Bn*nQB) + b*nQB + qblk  (ocg stride % 8 == 0 -> same-XCD tile
// replicas under round-robin dispatch -> L2 sharing of the input).
// Weights wave-uniform -> s_load. POOL: quad -> 1 pooled output/oc.
// Patch loads always in-bounds (2*qmax+3 <= IW-1 for all shapes used);
// all float2 addresses 8B-aligned (even strides/bases).
template <bool POOL, bool DO_SELU, bool DO_BIAS, int OCB>
__global__ __launch_bounds__(256) void k_conv3x3d(
    const float* __restrict__ in, const float* __restrict__ w,
    const float* __restrict__ bias, float* __restrict__ outA,
    float* __restrict__ outB, int splitB, int Bn, int Cin, int Cout, int IH,
    int IW, int nQB) {
  const int CH = IH - 2, CW = IW - 2;
  const int OH = POOL ? (CH >> 1) : CH;
  const int OW = POOL ? (CW >> 1) : CW;
  const int QY = POOL ? OH : (CH >> 1);
  const int QX = POOL ? OW : (CW >> 1);
  const int nQ = QY * QX;

  const int tpg = Bn * nQB;                 // tiles per ocg (divisible by 8)
  int bid = blockIdx.x;
  const int ocg = bid / tpg;
  const int rem = bid - ocg * tpg;
  const int b = rem / nQB;
  const int qblk = rem - b * nQB;
  const int oc0 = ocg * OCB;

  const int q = qblk * 256 + threadIdx.x;
  if (q >= nQ) return;
  const int qx = q % QX;
  const int qy = q / QX;
  const int iy = 2 * qy, ix = 2 * qx;

  const float* ib = in + ((long)b * Cin * IH + iy) * IW + ix;

  float acc[OCB][2][2];
#pragma unroll
  for (int o = 0; o < OCB; ++o)
#pragma unroll
    for (int r = 0; r < 2; ++r)
#pragma unroll
      for (int c = 0; c < 2; ++c) acc[o][r][c] = 0.f;

  for (int ci = 0; ci < Cin; ++ci) {
    float pr[4][4];
    const float* p = ib + (long)ci * IH * IW;
#pragma unroll
    for (int r = 0; r < 4; ++r) {
      const float2 u0 = *(const float2*)(p + (long)r * IW);
      const float2 u1 = *(const float2*)(p + (long)r * IW + 2);
      pr[r][0] = u0.x; pr[r][1] = u0.y; pr[r][2] = u1.x; pr[r][3] = u1.y;
    }
    const float* wc = w + ((long)oc0 * Cin + ci) * 9;  // wave-uniform
#pragma unroll
    for (int o = 0; o < OCB; ++o) {
      const float* wp = wc + (long)o * Cin * 9;
#pragma unroll
      for (int ky = 0; ky < 3; ++ky)
#pragma unroll
        for (int kx = 0; kx < 3; ++kx) {
          const float ww = wp[ky * 3 + kx];
#pragma unroll
          for (int r = 0; r < 2; ++r)
#pragma unroll
            for (int c = 0; c < 2; ++c)
              acc[o][r][c] = fmaf(ww, pr[r + ky][c + kx], acc[o][r][c]);
        }
    }
  }

  if (POOL) {
#pragma unroll
    for (int o = 0; o < OCB; ++o) {
      const float bb = DO_BIAS ? bias[oc0 + o] : 0.f;
      float s = 0.f;
#pragma unroll
      for (int r = 0; r < 2; ++r)
#pragma unroll
        for (int c = 0; c < 2; ++c) {
          float v = acc[o][r][c] + bb;
          if (DO_SELU) v = selu_f(v);
          s += v;
        }
      const float rv = 0.25f * s;
      const int oc = oc0 + o;
      if (outB != nullptr && b >= splitB)
        outB[(((long)(b - splitB) * Cout + oc) * OH + qy) * OW + qx] = rv;
      else
        outA[(((long)b * Cout + oc) * OH + qy) * OW + qx] = rv;
    }
  } else {
#pragma unroll
    for (int o = 0; o < OCB; ++o) {
      const float bb = DO_BIAS ? bias[oc0 + o] : 0.f;
      const int oc = oc0 + o;
#pragma unroll
      for (int r = 0; r < 2; ++r)
#pragma unroll
        for (int c = 0; c < 2; ++c) {
          const int oy = iy + r, ox = ix + c;
          float v = acc[o][r][c] + bb;
          if (DO_SELU) v = selu_f(v);
          float* dst =
              (outB != nullptr && b >= splitB)
                  ? &outB[(((long)(b - splitB) * Cout + oc) * OH + oy) * OW + ox]
                  : &outA[(((long)b * Cout + oc) * OH + oy) * OW + ox];
          *dst = v;
        }
    }
  }
}

// -------- qkv for MFMA attention -------------------------------------------
// qtb,ktb bf16 [Np][8]. V written PRE-PERMUTED into PV-fragment order:
// vp[((b*ntile + t)*CB + cb)*512 + lane*8 + i], lane = g*16 + (c&15),
// t = n>>5, mo = n&31, g = (mo&15)>>2, i = ((mo>>4)<<2) | (mo&3), cb = c>>4.
template <int CB>
__global__ __launch_bounds__(256) void k_qkvA(
    const float* __restrict__ x, const float* __restrict__ wq,
    const float* __restrict__ bq, const float* __restrict__ wk,
    const float* __restrict__ bk, const float* __restrict__ wv,
    const float* __restrict__ bv, unsigned short* __restrict__ qtb,
    unsigned short* __restrict__ ktb, unsigned short* __restrict__ vp,
    int Bn, int C, int D, int N, int Np) {
  constexpr int Cpad = CB * 16;
  const int ntile = Np >> 5;
  const int seg1 = Np * 8;
  const int S = 2 * seg1 + Cpad * Np;
  const int total = Bn * S;
  for (int idx = blockIdx.x * blockDim.x + threadIdx.x; idx < total;
       idx += gridDim.x * blockDim.x) {
    const int b = idx / S;
    const int rr = idx % S;
    const float* xb = x + (long)b * C * N;
    if (rr < 2 * seg1) {
      const bool isq = rr < seg1;
      const int t = isq ? rr : rr - seg1;
      const int n = t >> 3, co = t & 7;
      unsigned short val = 0;
      if (co < D && n < N) {
        const float* w = (isq ? wq : wk) + co * C;
        float a = (isq ? bq : bk)[co];
        for (int ci = 0; ci < C; ++ci) a = fmaf(w[ci], xb[(long)ci * N + n], a);
        val = (unsigned short)f2bf(a);
      }
      (isq ? qtb : ktb)[((long)b * Np + n) * 8 + co] = val;
    } else {
      const int t2 = rr - 2 * seg1;
      const int c = t2 / Np, n = t2 % Np;
      unsigned short v = 0;
      if (c < C && n < N) {
        const float* w = wv + c * C;
        float a = bv[c];
        for (int ci = 0; ci < C; ++ci) a = fmaf(w[ci], xb[(long)ci * N + n], a);
        v = (unsigned short)f2bf(a);
      }
      const int tt = n >> 5, mo = n & 31;
      const int g = (mo & 15) >> 2;
      const int i = ((mo >> 4) << 2) | (mo & 3);
      const int lane = g * 16 + (c & 15);
      const int cb = c >> 4;
      vp[(((long)b * ntile + tt) * CB + cb) * 512 + lane * 8 + i] = v;
    }
  }
}

// ---------------- full-MFMA flash attention + residual ----------------
template <int C, int CB>
__global__ __launch_bounds__(256) void k_attnN(
    const float* __restrict__ x, const unsigned short* __restrict__ qtb,
    const unsigned short* __restrict__ ktb,
    const unsigned short* __restrict__ vp,
    const float* __restrict__ gamma_p, float* __restrict__ out, int N, int Np,
    int nqt) {
  __shared__ float pO[4][CB * 256];
  __shared__ float pD[4][16];

  const int bid = blockIdx.x;
  const int b = bid / nqt;
  const int n0 = (bid % nqt) * 16;
  const int tid = threadIdx.x;
  const int wv_ = tid >> 6;
  const int lane = tid & 63;
  const int g = lane >> 4;
  const int qi = lane & 15;

  const int ntile = Np >> 5;
  const unsigned short* qb_ = qtb + (long)b * Np * 8;
  const unsigned short* kb_ = ktb + (long)b * Np * 8;
  const unsigned short* vb_ = vp + (long)b * ntile * CB * 512 + lane * 8;

  bf16x8 qf;
#pragma unroll
  for (int i = 0; i < 8; ++i) qf[i] = 0;
  if (g == 0) qf = *(const bf16x8*)(qb_ + (long)(n0 + qi) * 8);

  f32x4 acc[CB];
#pragma unroll
  for (int cb = 0; cb < CB; ++cb) {
    f32x4 z = {0.f, 0.f, 0.f, 0.f};
    acc[cb] = z;
  }
  float den = 0.f;
  const f32x4 z4 = {0.f, 0.f, 0.f, 0.f};

  for (int t = wv_; t < ntile; t += 4) {
    const int mb = t * 32;
    bf16x8 kf0, kf1;
#pragma unroll
    for (int i = 0; i < 8; ++i) { kf0[i] = 0; kf1[i] = 0; }
    if (g == 0) {
      kf0 = *(const bf16x8*)(kb_ + (long)(mb + qi) * 8);
      kf1 = *(const bf16x8*)(kb_ + (long)(mb + 16 + qi) * 8);
    }
    const f32x4 e0 =
        __builtin_amdgcn_mfma_f32_16x16x32_bf16(kf0, qf, z4, 0, 0, 0);
    const f32x4 e1 =
        __builtin_amdgcn_mfma_f32_16x16x32_bf16(kf1, qf, z4, 0, 0, 0);

    bf16x8 pb;
#pragma unroll
    for (int r = 0; r < 4; ++r) {
      const int ma = mb + 4 * g + r;
      const int mc = ma + 16;
      const float p0 = (ma < N) ? __expf(e0[r]) : 0.f;
      const float p1 = (mc < N) ? __expf(e1[r]) : 0.f;
      den += p0 + p1;
      pb[r] = f2bf(p0);
      pb[4 + r] = f2bf(p1);
    }
    const unsigned short* vt_ = vb_ + (long)t * CB * 512;
#pragma unroll
    for (int cb = 0; cb < CB; ++cb) {
      const bf16x8 va = *(const bf16x8*)(vt_ + cb * 512);
      acc[cb] =
          __builtin_amdgcn_mfma_f32_16x16x32_bf16(va, pb, acc[cb], 0, 0, 0);
    }
  }

  den += __shfl_xor(den, 16, 64);
  den += __shfl_xor(den, 32, 64);

#pragma unroll
  for (int cb = 0; cb < CB; ++cb)
#pragma unroll
    for (int r = 0; r < 4; ++r)
      pO[wv_][cb * 256 + (4 * g + r) * 16 + qi] = acc[cb][r];
  if (g == 0) pD[wv_][qi] = den;
  __syncthreads();

  const float gma = gamma_p[0];
#pragma unroll
  for (int cb = 0; cb < CB; ++cb) {
    const int cell = cb * 256 + tid;
    const int c = cb * 16 + (tid >> 4);
    const int q = tid & 15;
    const int n = n0 + q;
    if (c < C && n < N) {
      const float s = pO[0][cell] + pO[1][cell] + pO[2][cell] + pO[3][cell];
      const float Dn = pD[0][q] + pD[1][q] + pD[2][q] + pD[3][q];
      const long o = ((long)b * C + c) * N + n;
      out[o] = fmaf(gma, s / Dn, x[o]);
    }
  }
}

// ---------------- q/k/v projections (attn3 small path) ----------------
template <int Cp>
__global__ __launch_bounds__(256) void k_qkv3(
    const float* __restrict__ x, const float* __restrict__ wq,
    const float* __restrict__ bq, const float* __restrict__ wk,
    const float* __restrict__ bk, const float* __restrict__ wv,
    const float* __restrict__ bv, float* __restrict__ qt,
    float* __restrict__ kt, float* __restrict__ vt, int Bn, int C, int D,
    int N, int Np) {
  constexpr int KP = 8;
  const int S = Np * (2 * KP + Cp);
  const int total = Bn * S;
  for (int idx = blockIdx.x * blockDim.x + threadIdx.x; idx < total;
       idx += gridDim.x * blockDim.x) {
    const int b = idx / S;
    const int rr = idx % S;
    const float* xb = x + (long)b * C * N;
    const float* w = nullptr;
    const float* bp = nullptr;
    float* dst;
    int n, co, lim;
    if (rr < Np * KP) {
      n = rr / KP; co = rr % KP; lim = D;
      w = wq + co * C; bp = bq;
      dst = qt + ((long)b * Np + n) * KP + co;
    } else if (rr < 2 * Np * KP) {
      const int t = rr - Np * KP;
      n = t / KP; co = t % KP; lim = D;
      w = wk + co * C; bp = bk;
      dst = kt + ((long)b * Np + n) * KP + co;
    } else {
      const int t = rr - 2 * Np * KP;
      n = t / Cp; co = t % Cp; lim = C;
      w = wv + co * C; bp = bv;
      dst = vt + ((long)b * Np + n) * Cp + co;
    }
    if (co < lim && n < N) {
      float a = bp[co];
      for (int ci = 0; ci < C; ++ci) a = fmaf(w[ci], xb[(long)ci * N + n], a);
      *dst = a;
    } else {
      *dst = 0.f;
    }
  }
}

// ---------------- flash attention partials (attn3 small path) ---------------
template <int C, int Chp>
__global__ __launch_bounds__(128) void k_attn7(
    const float* __restrict__ qt, const float* __restrict__ kt,
    const float* __restrict__ vt, float* __restrict__ num,
    float* __restrict__ den, int N, int nbr, int S, int msz, int Np, int Nr) {
  constexpr int KP = 8;
  constexpr int Cp = 2 * Chp;
  constexpr int NV = Chp / 4;
  int bid = blockIdx.x;
  const int s = bid % S; bid /= S;
  const int rb = bid % nbr;
  const int b = bid / nbr;
  const int brow = rb * 32;
  const int tid = threadIdx.x;
  const int lane = tid & 63;
  const int cg = tid >> 6;
  const int g = lane >> 4;
  const int r = lane & 15;

  const float* qb = qt + (long)b * Np * KP;
  const float* kb = kt + (long)b * Np * KP;
  const float* vb = vt + (long)b * Np * Cp;

  float4 q0[2];
  float2 q1[2];
#pragma unroll
  for (int k = 0; k < 2; ++k) {
    const int n = brow + r + 16 * k;
    q0[k] = *(const float4*)(qb + (long)n * KP);
    q1[k] = *(const float2*)(qb + (long)n * KP + 4);
  }

  float acc[2][Chp];
#pragma unroll
  for (int k = 0; k < 2; ++k)
#pragma unroll
    for (int c = 0; c < Chp; ++c) acc[k][c] = 0.f;
  float sm[2] = {0.f, 0.f};

  const int mstart = s * msz;
  const int mlimit = min(mstart + msz, N);
  for (int m0 = mstart; m0 < mlimit; m0 += 4) {
    const int m = m0 + g;
    const float4 ka = *(const float4*)(kb + (long)m * KP);
    const float2 kc = *(const float2*)(kb + (long)m * KP + 4);
    float4 vv[NV];
    const float4* vpp = (const float4*)(vb + (long)m * Cp + cg * Chp);
#pragma unroll
    for (int j = 0; j < NV; ++j) vv[j] = vpp[j];
#pragma unroll
    for (int k = 0; k < 2; ++k) {
      float e = q0[k].x * ka.x;
      e = fmaf(q0[k].y, ka.y, e);
      e = fmaf(q0[k].z, ka.z, e);
      e = fmaf(q0[k].w, ka.w, e);
      e = fmaf(q1[k].x, kc.x, e);
      e = fmaf(q1[k].y, kc.y, e);
      const float p = __expf(e);
      sm[k] += p;
#pragma unroll
      for (int j = 0; j < NV; ++j) {
        acc[k][4 * j + 0] = fmaf(p, vv[j].x, acc[k][4 * j + 0]);
        acc[k][4 * j + 1] = fmaf(p, vv[j].y, acc[k][4 * j + 1]);
        acc[k][4 * j + 2] = fmaf(p, vv[j].z, acc[k][4 * j + 2]);
        acc[k][4 * j + 3] = fmaf(p, vv[j].w, acc[k][4 * j + 3]);
      }
    }
  }

#pragma unroll
  for (int k = 0; k < 2; ++k) {
    sm[k] += __shfl_xor(sm[k], 16, 64);
    sm[k] += __shfl_xor(sm[k], 32, 64);
#pragma unroll
    for (int c = 0; c < Chp; ++c) {
      acc[k][c] += __shfl_xor(acc[k][c], 16, 64);
      acc[k][c] += __shfl_xor(acc[k][c], 32, 64);
    }
  }

  if (g == 0) {
    float* np_ = num + ((long)(s * 8 + b) * Cp + cg * Chp) * Nr;
    float* dp_ = den + (long)(s * 8 + b) * Nr;
#pragma unroll
    for (int k = 0; k < 2; ++k) {
      const int n = brow + r + 16 * k;
      if (n < N) {
#pragma unroll
        for (int c = 0; c < Chp; ++c) np_[(long)c * Nr + n] = acc[k][c];
        if (cg == 0) dp_[n] = sm[k];
      }
    }
  }
}

// ---------------- attention merge (attn3 small path) ----------------
__global__ __launch_bounds__(256) void k_attnmerge(
    const float* __restrict__ x, const float* __restrict__ num,
    const float* __restrict__ den, const float* __restrict__ gamma_p,
    float* __restrict__ out, int C, int Cp, int N, int Nr, int S) {
  const float g = gamma_p[0];
  const int total = 8 * C * N;
  for (int idx = blockIdx.x * blockDim.x + threadIdx.x; idx < total;
       idx += gridDim.x * blockDim.x) {
    const int n = idx % N;
    const int t = idx / N;
    const int c = t % C;
    const int b = t / C;
    float a = 0.f, d = 0.f;
    for (int s = 0; s < S; ++s) {
      a += num[((long)(s * 8 + b) * Cp + c) * Nr + n];
      d += den[(long)(s * 8 + b) * Nr + n];
    }
    out[((long)b * C + c) * N + n] =
        fmaf(g, a / d, x[((long)b * C + c) * N + n]);
  }
}

// ---------------- batchnorm stats: mean + rsqrt(var+eps) per channel --------
__global__ __launch_bounds__(256) void k_bnstats(const float* __restrict__ x,
                                                 float* __restrict__ stats,
                                                 int Bn, int C, int HW,
                                                 float eps) {
  int c = blockIdx.x;
  int tid = threadIdx.x;
  int cnt = Bn * HW;
  float s = 0.f, s2 = 0.f;
  for (int i = tid; i < cnt; i += blockDim.x) {
    int b = i / HW, r = i % HW;
    float v = x[((long)b * C + c) * HW + r];
    s += v;
    s2 += v * v;
  }
#pragma unroll
  for (int off = 32; off > 0; off >>= 1) {
    s += __shfl_down(s, off);
    s2 += __shfl_down(s2, off);
  }
  __shared__ float as_[4], as2_[4];
  int wid = tid >> 6;
  if ((tid & 63) == 0) { as_[wid] = s; as2_[wid] = s2; }
  __syncthreads();
  if (tid == 0) {
    float S = 0.f, S2 = 0.f;
#pragma unroll
    for (int ww = 0; ww < 4; ++ww) { S += as_[ww]; S2 += as2_[ww]; }
    float mean = S / (float)cnt;
    float var = S2 / (float)cnt - mean * mean;
    stats[c] = mean;
    stats[C + c] = rsqrtf(var + eps);
  }
}

// ---------------- BN apply + selu (+pool) ----------------
template <bool POOL>
__global__ __launch_bounds__(256) void k_bn_selu(
    const float* __restrict__ x, const float* __restrict__ stats,
    const float* __restrict__ g, const float* __restrict__ beta,
    float* __restrict__ out, int Bn, int C, int IH, int IW) {
  int OH = POOL ? (IH >> 1) : IH;
  int OW = POOL ? (IW >> 1) : IW;
  int total = Bn * C * OH * OW;
  for (int idx = blockIdx.x * blockDim.x + threadIdx.x; idx < total;
       idx += gridDim.x * blockDim.x) {
    int px = idx % OW;
    int t = idx / OW;
    int py = t % OH;
    t /= OH;
    int c = t % C;
    int b = t / C;
    float mean = stats[c], istd = stats[C + c];
    float gg = g[c], bb = beta[c];
    const float* ip = x + ((long)b * C + c) * IH * IW;
    float r;
    if (POOL) {
      int iy = py * 2, ix = px * 2;
      float v00 = selu_f((ip[iy * IW + ix] - mean) * istd * gg + bb);
      float v01 = selu_f((ip[iy * IW + ix + 1] - mean) * istd * gg + bb);
      float v10 = selu_f((ip[(iy + 1) * IW + ix] - mean) * istd * gg + bb);
      float v11 = selu_f((ip[(iy + 1) * IW + ix + 1] - mean) * istd * gg + bb);
      r = 0.25f * (v00 + v01 + v10 + v11);
    } else {
      r = selu_f((ip[py * IW + px] - mean) * istd * gg + bb);
    }
    out[((b * C + c) * OH + py) * OW + px] = r;
  }
}

static inline int gs(int total) { return (total + 255) / 256; }
static inline int cdiv(int a, int b) { return (a + b - 1) / b; }

extern "C" void kernel_launch(void* const* d_in, const int* in_sizes, int n_in,
                              void* d_out, int out_size, void* d_ws,
                              size_t ws_size, hipStream_t stream) {
  const float* x      = (const float*)d_in[0];
  const float* enc_w1 = (const float*)d_in[1];
  const float* enc_b1 = (const float*)d_in[2];
  const float* enc_w2 = (const float*)d_in[3];
  const float* enc_b2 = (const float*)d_in[4];
  const float* a1_wq  = (const float*)d_in[5];
  const float* a1_bq  = (const float*)d_in[6];
  const float* a1_wk  = (const float*)d_in[7];
  const float* a1_bk  = (const float*)d_in[8];
  const float* a1_wv  = (const float*)d_in[9];
  const float* a1_bv  = (const float*)d_in[10];
  const float* a1_g   = (const float*)d_in[11];
  const float* c1_w   = (const float*)d_in[12];
  const float* c1_b   = (const float*)d_in[13];
  const float* a2_wq  = (const float*)d_in[14];
  const float* a2_bq  = (const float*)d_in[15];
  const float* a2_wk  = (const float*)d_in[16];
  const float* a2_bk  = (const float*)d_in[17];
  const float* a2_wv  = (const float*)d_in[18];
  const float* a2_bv  = (const float*)d_in[19];
  const float* a2_g   = (const float*)d_in[20];
  const float* c2_w   = (const float*)d_in[21];
  const float* c2_b   = (const float*)d_in[22];
  const float* c3_w   = (const float*)d_in[23];
  const float* c3_g   = (const float*)d_in[24];
  const float* c3_be  = (const float*)d_in[25];
  const float* c4_w   = (const float*)d_in[26];
  const float* c4_g   = (const float*)d_in[27];
  const float* c4_be  = (const float*)d_in[28];
  const float* a3_wq  = (const float*)d_in[29];
  const float* a3_bq  = (const float*)d_in[30];
  const float* a3_wk  = (const float*)d_in[31];
  const float* a3_bk  = (const float*)d_in[32];
  const float* a3_wv  = (const float*)d_in[33];
  const float* a3_bv  = (const float*)d_in[34];
  const float* a3_g   = (const float*)d_in[35];

  float* out = (float*)d_out;
  float* W = (float*)d_ws;

  // ---- workspace plan (float slots; peak 5,056,320 = 20.2 MB, proven) ----
  float* h    = W;                         // [0, 1,920,000)
  float* h1   = W + 1920000;               // [1,920,000, 5,056,320)
  float* h2   = W;                         // [0, 737,280)
  float* xenc = out + 5120;                // (8,40,48,48) direct

  // attn1: Np1=2304, CB=3
  unsigned short* qtb1 = (unsigned short*)(W + 737280);   // 147,456 bf16
  unsigned short* ktb1 = (unsigned short*)(W + 884736);   // 147,456 bf16
  unsigned short* vtb1 = (unsigned short*)(W + 1032192);  // 884,736 bf16
  float* at1 = W + 1474560;                // 737,280 -> ends 2,211,840
  float* c1o = W + 2211840;                // 846,400 -> ends 3,058,240

  // attn2: Np2=2144, CB=4
  unsigned short* qtb2 = (unsigned short*)(W + 3058240);  // 137,216 bf16
  unsigned short* ktb2 = (unsigned short*)(W + 3195456);  // 137,216 bf16
  unsigned short* vtb2 = (unsigned short*)(W + 3332672);  // 1,097,728 bf16
  float* at2 = W + 3881536;                // 846,400 -> ends 4,727,936

  float* c2o  = W;                         // 154,880
  float* c3o  = W + 200000;                // 96,000
  float* st3  = W + 300000;                // 60
  float* c3p  = W + 310000;                // 24,000
  float* c4o  = W + 340000;                // 5,120
  float* st4  = W + 350000;                // 20
  float* c4b  = W + 360000;                // 5,120
  float* q3   = W + 370000;                // 8,192
  float* k3   = W + 380000;                // 8,192
  float* v3   = W + 390000;                // 16,384
  float* num3 = W + 410000;                // 8,192
  float* den3 = W + 420000;                // 512

  const int NOSPLIT = 1 << 30;

  // 1. prep
  {
    int n = 8 * 3 * 200 * 200;
    k_prep<<<gs(n), 256, 0, stream>>>(x, h, n);
  }
  // 2. enc conv1 + selu + pool : (16,3,200,200)->(16,20,99,99), direct OCB=5
  {
    int nQ = 99 * 99;
    int nQB = cdiv(nQ, 256);               // 39 ; tpg = 16*39 = 624 (%8==0)
    int blocks = 16 * (20 / 5) * nQB;      // 2496
    k_conv3x3d<true, true, true, 5><<<blocks, 256, 0, stream>>>(
        h, enc_w1, enc_b1, h1, nullptr, NOSPLIT, 16, 3, 20, 200, 200, nQB);
  }
  // 3. enc conv2 + selu + pool : (16,20,99,99)->(16,40,48,48), direct OCB=5
  {
    int nQ = 48 * 48;
    int nQB = cdiv(nQ, 256);               // 9 ; tpg = 16*9 = 144 (%8==0)
    int blocks = 16 * (40 / 5) * nQB;      // 1152
    k_conv3x3d<true, true, true, 5><<<blocks, 256, 0, stream>>>(
        h1, enc_w2, enc_b2, h2, xenc, 8, 16, 20, 40, 99, 99, nQB);
  }
  // 4. attn1 qkv : CB=3, Np=2304
  {
    int total = 8 * 2304 * (16 + 48);
    k_qkvA<3><<<gs(total), 256, 0, stream>>>(h2, a1_wq, a1_bq, a1_wk, a1_bk,
                                             a1_wv, a1_bv, qtb1, ktb1, vtb1,
                                             8, 40, 5, 2304, 2304);
  }
  // 5. attn1 (full MFMA, coalesced V) : C=40, CB=3, nqt=144
  {
    k_attnN<40, 3><<<8 * 144, 256, 0, stream>>>(h2, qtb1, ktb1, vtb1, a1_g,
                                                at1, 2304, 2304, 144);
  }
  // 6. c1 conv + selu : (8,40,48,48)->(8,50,46,46), direct OCB=2
  {
    int nQ = 23 * 23;                      // quads over 46x46
    int nQB = cdiv(nQ, 256);               // 3 ; tpg = 8*3 = 24 (%8==0)
    int blocks = 8 * (50 / 2) * nQB;       // 600
    k_conv3x3d<false, true, true, 2><<<blocks, 256, 0, stream>>>(
        at1, c1_w, c1_b, c1o, nullptr, NOSPLIT, 8, 40, 50, 48, 48, nQB);
  }
  // 7. attn2 qkv : CB=4, Np=2144
  {
    int total = 8 * 2144 * (16 + 64);
    k_qkvA<4><<<gs(total), 256, 0, stream>>>(c1o, a2_wq, a2_bq, a2_wk, a2_bk,
                                             a2_wv, a2_bv, qtb2, ktb2, vtb2,
                                             8, 50, 6, 2116, 2144);
  }
  // 8. attn2 (full MFMA, coalesced V) : C=50, CB=4, nqt=133
  {
    k_attnN<50, 4><<<8 * 133, 256, 0, stream>>>(c1o, qtb2, ktb2, vtb2, a2_g,
                                                at2, 2116, 2144, 133);
  }
  // 9. c2 conv + selu + pool : (8,50,46,46)->(8,40,22,22), direct OCB=2
  {
    int nQ = 22 * 22;                      // pooled outputs
    int nQB = cdiv(nQ, 256);               // 2 ; tpg = 8*2 = 16 (%8==0)
    int blocks = 8 * (40 / 2) * nQB;       // 320
    k_conv3x3d<true, true, true, 2><<<blocks, 256, 0, stream>>>(
        at2, c2_w, c2_b, c2o, nullptr, NOSPLIT, 8, 50, 40, 46, 46, nQB);
  }
  // 10. c3 conv : (8,40,22,22)->(8,30,20,20), direct OCB=2
  {
    int nQ = 10 * 10;
    int nQB = cdiv(nQ, 256);               // 1 ; tpg = 8 (%8==0)
    int blocks = 8 * (30 / 2) * nQB;       // 120
    k_conv3x3d<false, false, false, 2><<<blocks, 256, 0, stream>>>(
        c2o, c3_w, nullptr, c3o, nullptr, NOSPLIT, 8, 40, 30, 22, 22, nQB);
  }
  // 11-12. BN(c3) + selu + pool -> (8,30,10,10)
  k_bnstats<<<30, 256, 0, stream>>>(c3o, st3, 8, 30, 400, 1e-5f);
  {
    int total = 8 * 30 * 10 * 10;
    k_bn_selu<true><<<gs(total), 256, 0, stream>>>(c3o, st3, c3_g, c3_be, c3p,
                                                   8, 30, 20, 20);
  }
  // 13. c4 conv : (8,30,10,10)->(8,10,8,8), direct OCB=2
  {
    int nQ = 4 * 4;
    int nQB = cdiv(nQ, 256);               // 1 ; tpg = 8 (%8==0)
    int blocks = 8 * (10 / 2) * nQB;       // 40
    k_conv3x3d<false, false, false, 2><<<blocks, 256, 0, stream>>>(
        c3p, c4_w, nullptr, c4o, nullptr, NOSPLIT, 8, 30, 10, 10, 10, nQB);
  }
  // 14-15. BN(c4) + selu
  k_bnstats<<<10, 256, 0, stream>>>(c4o, st4, 8, 10, 64, 1e-5f);
  {
    int total = 8 * 10 * 8 * 8;
    k_bn_selu<false><<<gs(total), 256, 0, stream>>>(c4o, st4, c4_g, c4_be, c4b,
                                                    8, 10, 8, 8);
  }
  // 16. attn3 qkv : Cp=16, Np=128
  {
    int total = 8 * 128 * (16 + 16);
    k_qkv3<16><<<gs(total), 256, 0, stream>>>(c4b, a3_wq, a3_bq, a3_wk, a3_bk,
                                              a3_wv, a3_bv, q3, k3, v3, 8, 10,
                                              1, 64, 128);
  }
  // 17. attn3 partials + merge -> out[0..5120)
  {
    int nbr = 2, S = 1, msz = 64;
    k_attn7<10, 8><<<8 * nbr * S, 128, 0, stream>>>(q3, k3, v3, num3, den3, 64,
                                                    nbr, S, msz, 128, 64);
    k_attnmerge<<<gs(8 * 10 * 64), 256, 0, stream>>>(c4b, num3, den3, a3_g,
                                                     out, 10, 16, 64, 64, S);
  }
}